// Round 18
// baseline (440.130 us; speedup 1.0000x reference)
//
#include <hip/hip_runtime.h>

typedef _Float16 half8 __attribute__((ext_vector_type(8)));
typedef _Float16 half4 __attribute__((ext_vector_type(4)));
typedef _Float16 half2v __attribute__((ext_vector_type(2)));
typedef float f32x4 __attribute__((ext_vector_type(4)));

#define LOG2E 1.4426950408889634f
#define QSCALE (0.17677669529663687f * 1.4426950408889634f)

static __device__ __forceinline__ half4 cvt4h(float4 v) {
    half2v a = __builtin_bit_cast(half2v, __builtin_amdgcn_cvt_pkrtz(v.x, v.y));
    half2v b = __builtin_bit_cast(half2v, __builtin_amdgcn_cvt_pkrtz(v.z, v.w));
    return half4{ a[0], a[1], b[0], b[1] };
}

// ---------------- fused convert + prep ----------------
// W pre-fragmented in MFMA B-operand order (R16-verified):
//   Wt[(row>>4)*8192 + (col>>5)*512 + (((col>>3)&3)*16 + (row&15))*8 + col%8]
//     = W[row][col]
// so one wave loads a B-fragment (16 cols x 32 k) as a single 1KB load.
#define NB_X 16384
#define NB_Y 16384
#define NB_W 512
#define NB_M 4096
#define NB_R 4096

__global__ __launch_bounds__(256) void convert_kernel(
    const float* __restrict__ x, const float* __restrict__ y,
    const float* __restrict__ q_w, const float* __restrict__ kv_w,
    const float* __restrict__ proj_w, const float* __restrict__ mask,
    const float* __restrict__ table, const int* __restrict__ rpi,
    _Float16* __restrict__ Xh, _Float16* __restrict__ Yh,
    _Float16* __restrict__ Wt, _Float16* __restrict__ maskh,
    _Float16* __restrict__ rpbh)
{
    const int blk = blockIdx.x, t = threadIdx.x;
    if (blk < NB_X + NB_Y) {
        const float* src; _Float16* dst; int v;
        if (blk < NB_X) { v = blk * 256 + t; src = x; dst = Xh; }
        else { v = (blk - NB_X) * 256 + t; src = y; dst = Yh; }
        int r = v >> 6, ks = (v & 63) * 8;
        const float* s = src + ((size_t)(r >> 8) * 512 + (size_t)((r & 255) * 2)) * 512 + ks;
        half4 h0 = cvt4h(*(const float4*)s);
        half4 h1 = cvt4h(*(const float4*)(s + 4));
        half8 hv = { h0[0], h0[1], h0[2], h0[3], h1[0], h1[1], h1[2], h1[3] };
        *(half8*)(dst + (size_t)v * 8) = hv;
    } else if (blk < NB_X + NB_Y + NB_W) {
        int v = (blk - NB_X - NB_Y) * 256 + t;
        int row = v >> 6, c8 = v & 63;
        const float* s; float sc = 1.0f;
        if (row < 512)       { s = q_w + (size_t)row * 512;            sc = QSCALE; }
        else if (row < 1536) { s = kv_w + (size_t)(row - 512) * 512; }
        else                 { s = proj_w + (size_t)(row - 1536) * 512; }
        float4 a = *(const float4*)(s + c8 * 8);
        float4 b = *(const float4*)(s + c8 * 8 + 4);
        a.x *= sc; a.y *= sc; a.z *= sc; a.w *= sc;
        b.x *= sc; b.y *= sc; b.z *= sc; b.w *= sc;
        half4 h0 = cvt4h(a), h1 = cvt4h(b);
        half8 hv = { h0[0], h0[1], h0[2], h0[3], h1[0], h1[1], h1[2], h1[3] };
        int off = (row >> 4) * 8192 + (c8 >> 2) * 512 + ((c8 & 3) * 16 + (row & 15)) * 8;
        *(half8*)(Wt + off) = hv;
    } else if (blk < NB_X + NB_Y + NB_W + NB_M) {
        int i = (blk - NB_X - NB_Y - NB_W) * 256 + t;
        float4 v = ((const float4*)mask)[i];
        half4 hv = { (_Float16)(v.x * LOG2E), (_Float16)(v.y * LOG2E),
                     (_Float16)(v.z * LOG2E), (_Float16)(v.w * LOG2E) };
        *(half4*)(maskh + (size_t)i * 4) = hv;
    } else {
        int i = (blk - NB_X - NB_Y - NB_W - NB_M) * 256 + t;
        int p = i & 65535, hh = i >> 16;
        rpbh[i] = (_Float16)(table[rpi[p] * 16 + hh] * LOG2E);
    }
}

// ---------------- pipelined f16 GEMM: A via LDS, W via PREFETCHED frags ------
// C[r][c] = A[r][:] . W[c][:] + bias, K=512, tile 128x128, BK=64.
// A: R10/R15 pipelined reg-stage -> swizzled LDS.  W: register double-buffer
// of pre-fragmented 1KB loads, prefetched one K-step ahead (issued during
// MFMA(kk), consumed at MFMA(kk+1)) -- halves ds-instr count vs R15 while
// keeping every load latency-hidden (R16's failure mode was no prefetch).
// Epilogue: R15-verified coalesced f16 path (modes 0/1) / direct fp32 (mode 2).
__global__ __launch_bounds__(256) void gemm_f16(
    const _Float16* __restrict__ Ah, const _Float16* __restrict__ Wt,
    const float* __restrict__ bias, float bscale,
    _Float16* __restrict__ qout, _Float16* __restrict__ kout,
    _Float16* __restrict__ vout, float* __restrict__ fout,
    int mode, int nct_sh, int nbo)
{
    __shared__ __align__(16) _Float16 S[128 * 128];      // 32 KB
    _Float16* As = S;                                    // staging uses 16 KB
    const int nwg = gridDim.x;
    const int chunk = nwg >> 3;
    const int f = blockIdx.x;
    const int swz = (f & 7) * chunk + (f >> 3);
    const int ct = swz & ((1 << nct_sh) - 1);
    const int rt = swz >> nct_sh;

    const int t = threadIdx.x;
    const int lane = t & 63, wave = t >> 6;
    const int ql = lane & 15, g = lane >> 4;
    const int wr = (wave >> 1) * 64, wc = (wave & 1) * 64;

    const int sr = t >> 3;
    const int st = t & 7;
    const _Float16* aR = Ah + ((size_t)(rt * 128 + sr)) * 512 + st * 8;
    char* asw = (char*)As + sr * 128 + ((st ^ (sr & 7)) << 4);

    // W fragment bases
    const _Float16* wtp[4];
#pragma unroll
    for (int j = 0; j < 4; ++j) {
        int nb = nbo + ct * 8 + (wc >> 4) + j;
        wtp[j] = Wt + (size_t)nb * 8192 + lane * 8;
    }

    // prologue: A(0) and W(0)
    half8 a0 = *(const half8*)(aR);
    half8 a1 = *(const half8*)(aR + 32 * 512);
    half8 a2 = *(const half8*)(aR + 64 * 512);
    half8 a3 = *(const half8*)(aR + 96 * 512);
    half8 wc0[4], wc1[4], wn0[4], wn1[4];
#pragma unroll
    for (int j = 0; j < 4; ++j) {
        wc0[j] = *(const half8*)(wtp[j]);
        wc1[j] = *(const half8*)(wtp[j] + 512);
    }

    f32x4 acc[4][4] = {};
    for (int kk = 0; kk < 8; ++kk) {
        if (kk) __syncthreads();           // prior tile's LDS reads finished
        *(half8*)(asw)           = a0;
        *(half8*)(asw + 32*128)  = a1;
        *(half8*)(asw + 64*128)  = a2;
        *(half8*)(asw + 96*128)  = a3;
        __syncthreads();
        if (kk < 7) {                      // prefetch next A + W EARLY
            const int k0n = (kk + 1) * 64;
            a0 = *(const half8*)(aR + k0n);
            a1 = *(const half8*)(aR + 32 * 512 + k0n);
            a2 = *(const half8*)(aR + 64 * 512 + k0n);
            a3 = *(const half8*)(aR + 96 * 512 + k0n);
#pragma unroll
            for (int j = 0; j < 4; ++j) {
                wn0[j] = *(const half8*)(wtp[j] + (kk + 1) * 1024);
                wn1[j] = *(const half8*)(wtp[j] + (kk + 1) * 1024 + 512);
            }
        }
#pragma unroll
        for (int kh = 0; kh < 2; ++kh) {
            half8 af[4];
#pragma unroll
            for (int i = 0; i < 4; ++i) {
                int row = wr + i * 16 + ql;
                af[i] = *(const half8*)((const char*)As + row * 128 +
                        (((kh * 4 + g) ^ (ql & 7)) << 4));
            }
#pragma unroll
            for (int i = 0; i < 4; ++i)
#pragma unroll
                for (int j = 0; j < 4; ++j)
                    acc[i][j] = __builtin_amdgcn_mfma_f32_16x16x32_f16(
                        af[i], kh ? wc1[j] : wc0[j], acc[i][j], 0, 0, 0);
        }
        if (kk < 7) {
#pragma unroll
            for (int j = 0; j < 4; ++j) { wc0[j] = wn0[j]; wc1[j] = wn1[j]; }
        }
    }

    if (mode == 2) {
#pragma unroll
        for (int j = 0; j < 4; ++j) {
            int c = ct * 128 + wc + j * 16 + ql;
            float bv = bias[c];
#pragma unroll
            for (int i = 0; i < 4; ++i)
#pragma unroll
                for (int rr = 0; rr < 4; ++rr) {
                    int r = rt * 128 + wr + i * 16 + g * 4 + rr;
                    fout[(size_t)r * 512 + c] = acc[i][j][rr] + bv;
                }
        }
        return;
    }

    // ---- coalesced f16 epilogue (R15-verified) ----
    __syncthreads();
#pragma unroll
    for (int j = 0; j < 4; ++j) {
        int col = wc + j * 16 + ql;
        float bv = bias[ct * 128 + col] * bscale;
#pragma unroll
        for (int i = 0; i < 4; ++i) {
#pragma unroll
            for (int rr = 0; rr < 4; ++rr) {
                int row = wr + i * 16 + g * 4 + rr;
                int scol = col ^ (((row >> 2) & 3) << 4);
                S[row * 128 + scol] = (_Float16)(acc[i][j][rr] + bv);
            }
        }
    }
    __syncthreads();
    {
        const int c0 = ct * 128 + wave * 32;
        const int b = (rt * 128) >> 8, n0 = (rt * 128) & 255;
        _Float16* dst;
        int cc = c0;
        if (mode == 0) { dst = qout; }
        else if (c0 < 512) { dst = kout; }
        else { dst = vout; cc = c0 - 512; }
        const int hw = cc >> 5;
        _Float16* gb = dst + ((size_t)(b * 16 + hw) * 256 + n0) * 32;
        const int dq = (lane & 3) * 8;
#pragma unroll
        for (int m = 0; m < 8; ++m) {
            int n = m * 16 + (lane >> 2);
            int colb = wave * 32 + dq;
            int scol = colb ^ (((n >> 2) & 3) << 4);
            half8 v = *(const half8*)(S + n * 128 + scol);
            *(half8*)(gb + (size_t)n * 32 + dq) = v;
        }
    }
}

// ---------------- fused window attention (R15-verified) ----------------------
__global__ __launch_bounds__(256, 2) void attn_kernel(
    const _Float16* __restrict__ Q, const _Float16* __restrict__ K,
    const _Float16* __restrict__ V, const _Float16* __restrict__ rpbh,
    const _Float16* __restrict__ maskh, _Float16* __restrict__ pre)
{
    __shared__ __align__(16) _Float16 bias_s[2][16 * 256];   // 2 x 8 KB
    const int blk = blockIdx.x;
    const int w = blk >> 4, h = blk & 15;
    const int t = threadIdx.x;
    const int lane = t & 63, wave = t >> 6;
    const int ql = lane & 15, g = lane >> 4;
    const int b = w + 64 * wave;
    const size_t blk_b = (size_t)(b * 16 + h) * 8192;
    const _Float16* Qp = Q + blk_b + g * 8;
    const _Float16* Kp = K + blk_b + ql * 32 + g * 8;
    const _Float16* rp = rpbh + (size_t)h * 65536;
    const _Float16* mp = maskh + (size_t)w * 65536;

    half8 karr[16];
#pragma unroll
    for (int tt = 0; tt < 16; ++tt)
        karr[tt] = *(const half8*)(Kp + tt * 512);

    half4 vf0[16], vf1[16];
    {
        const _Float16* vb = V + blk_b + g * 128 + ql;
#pragma unroll
        for (int tt = 0; tt < 16; ++tt) {
#pragma unroll
            for (int j = 0; j < 4; ++j) {
                vf0[tt][j] = vb[tt * 512 + j * 32];
                vf1[tt][j] = vb[tt * 512 + j * 32 + 16];
            }
        }
    }

    const int sq = t >> 4;
    const int scb = (t & 15) * 32;
    const int sw = sq << 3;
    const int sgoff = (t & 15) * 16;

    {
        const _Float16* rrow = rp + (size_t)sq * 256 + sgoff;
        const _Float16* mrow = mp + (size_t)sq * 256 + sgoff;
        half8 s0 = *(const half8*)rrow + *(const half8*)mrow;
        half8 s1 = *(const half8*)(rrow + 8) + *(const half8*)(mrow + 8);
        char* sb = (char*)bias_s[0] + sq * 512;
        *(half4*)(sb + ((scb) ^ sw))      = __builtin_shufflevector(s0, s0, 0, 1, 2, 3);
        *(half4*)(sb + ((scb + 8) ^ sw))  = __builtin_shufflevector(s0, s0, 4, 5, 6, 7);
        *(half4*)(sb + ((scb + 16) ^ sw)) = __builtin_shufflevector(s1, s1, 0, 1, 2, 3);
        *(half4*)(sb + ((scb + 24) ^ sw)) = __builtin_shufflevector(s1, s1, 4, 5, 6, 7);
    }
    __syncthreads();

#pragma unroll 1
    for (int qg = 0; qg < 16; ++qg) {
        const int q0 = qg * 16;
        half8 nr0, nm0, nr1, nm1;
        if (qg < 15) {
            const _Float16* rrow = rp + (size_t)(q0 + 16 + sq) * 256 + sgoff;
            const _Float16* mrow = mp + (size_t)(q0 + 16 + sq) * 256 + sgoff;
            nr0 = *(const half8*)rrow;
            nm0 = *(const half8*)mrow;
            nr1 = *(const half8*)(rrow + 8);
            nm1 = *(const half8*)(mrow + 8);
        }

        const int q = q0 + ql;
        half8 qf = *(const half8*)(Qp + (size_t)q * 32);
        const char* bb = (const char*)bias_s[qg & 1] + ql * 512;
        f32x4 lsum = { 0.f, 0.f, 0.f, 0.f };
        f32x4 o0 = { 0.f, 0.f, 0.f, 0.f }, o1 = { 0.f, 0.f, 0.f, 0.f };
#pragma unroll
        for (int tt = 0; tt < 16; ++tt) {
            half4 bs = *(const half4*)(bb + ((tt * 32 + g * 8) ^ (ql << 3)));
            f32x4 bf = { (float)bs[0], (float)bs[1], (float)bs[2], (float)bs[3] };
            f32x4 s = __builtin_amdgcn_mfma_f32_16x16x32_f16(karr[tt], qf, bf, 0, 0, 0);
            float e0 = __builtin_amdgcn_exp2f(s[0]);
            float e1 = __builtin_amdgcn_exp2f(s[1]);
            float e2 = __builtin_amdgcn_exp2f(s[2]);
            float e3 = __builtin_amdgcn_exp2f(s[3]);
            lsum[0] += e0; lsum[1] += e1; lsum[2] += e2; lsum[3] += e3;
            half2v p01 = __builtin_bit_cast(half2v, __builtin_amdgcn_cvt_pkrtz(e0, e1));
            half2v p23 = __builtin_bit_cast(half2v, __builtin_amdgcn_cvt_pkrtz(e2, e3));
            half4 pf = { p01[0], p01[1], p23[0], p23[1] };
            o0 = __builtin_amdgcn_mfma_f32_16x16x16f16(pf, vf0[tt], o0, 0, 0, 0);
            o1 = __builtin_amdgcn_mfma_f32_16x16x16f16(pf, vf1[tt], o1, 0, 0, 0);
        }
        float l = (lsum[0] + lsum[1]) + (lsum[2] + lsum[3]);
        l += __shfl_xor(l, 16);
        l += __shfl_xor(l, 32);
#pragma unroll
        for (int rr = 0; rr < 4; ++rr) {
            float inv = __builtin_amdgcn_rcpf(__shfl(l, g * 4 + rr));
            int row = q0 + g * 4 + rr;
            size_t ob = ((size_t)b * 256 + row) * 512 + h * 32;
            pre[ob + ql] = (_Float16)(o0[rr] * inv);
            pre[ob + 16 + ql] = (_Float16)(o1[rr] * inv);
        }
        if (qg < 15) {
            half8 s0 = nr0 + nm0, s1 = nr1 + nm1;
            char* sb = (char*)bias_s[(qg + 1) & 1] + sq * 512;
            *(half4*)(sb + ((scb) ^ sw))      = __builtin_shufflevector(s0, s0, 0, 1, 2, 3);
            *(half4*)(sb + ((scb + 8) ^ sw))  = __builtin_shufflevector(s0, s0, 4, 5, 6, 7);
            *(half4*)(sb + ((scb + 16) ^ sw)) = __builtin_shufflevector(s1, s1, 0, 1, 2, 3);
            *(half4*)(sb + ((scb + 24) ^ sw)) = __builtin_shufflevector(s1, s1, 4, 5, 6, 7);
        }
        __syncthreads();
    }
}

extern "C" void kernel_launch(void* const* d_in, const int* in_sizes, int n_in,
                              void* d_out, int out_size, void* d_ws, size_t ws_size,
                              hipStream_t stream)
{
    const float* x      = (const float*)d_in[0];
    const float* y      = (const float*)d_in[1];
    const float* mask   = (const float*)d_in[2];
    const float* q_w    = (const float*)d_in[3];
    const float* q_b    = (const float*)d_in[4];
    const float* kv_w   = (const float*)d_in[5];
    const float* kv_b   = (const float*)d_in[6];
    const float* proj_w = (const float*)d_in[7];
    const float* proj_b = (const float*)d_in[8];
    const float* btab   = (const float*)d_in[9];
    const int*   rpi    = (const int*)d_in[10];
    float* out = (float*)d_out;

    char* ws = (char*)d_ws;
    // aliased regions (sequential kernel ordering makes reuse safe):
    _Float16* XK  = (_Float16*)(ws);                       // Xh, then K
    _Float16* YP  = (_Float16*)(ws + ((size_t)64 << 20));  // Yh, then Pre
    _Float16* Qw  = (_Float16*)(ws + ((size_t)128 << 20));
    _Float16* Vw  = (_Float16*)(ws + ((size_t)192 << 20));
    _Float16* Wt  = (_Float16*)(ws + ((size_t)256 << 20));              // 2 MiB
    _Float16* Rpb = (_Float16*)(ws + ((size_t)258 << 20));              // 2 MiB
    _Float16* Mh  = (_Float16*)(ws + ((size_t)260 << 20));              // 8 MiB

    convert_kernel<<<NB_X + NB_Y + NB_W + NB_M + NB_R, 256, 0, stream>>>(
        x, y, q_w, kv_w, proj_w, mask, btab, rpi, XK, YP, Wt, Mh, Rpb);
    // Q projection [nbo=0]
    gemm_f16<<<2048, 256, 0, stream>>>(XK, Wt, q_b, QSCALE,
                                       Qw, nullptr, nullptr, nullptr, 0, 2, 0);
    // KV projection (K overwrites Xh) [nbo=32]
    gemm_f16<<<4096, 256, 0, stream>>>(YP, Wt, kv_b, 1.0f,
                                       nullptr, XK, Vw, nullptr, 1, 3, 32);
    // attention (Pre overwrites Yh)
    attn_kernel<<<1024, 256, 0, stream>>>(Qw, XK, Vw, Rpb, Mh, YP);
    // output projection [nbo=96]
    gemm_f16<<<2048, 256, 0, stream>>>(YP, Wt, proj_b, 1.0f,
                                       nullptr, nullptr, nullptr, out, 2, 2, 96);
}

// Round 19
// 418.361 us; speedup vs baseline: 1.0520x; 1.0520x over previous
//
#include <hip/hip_runtime.h>

typedef _Float16 half8 __attribute__((ext_vector_type(8)));
typedef _Float16 half4 __attribute__((ext_vector_type(4)));
typedef _Float16 half2v __attribute__((ext_vector_type(2)));
typedef float f32x4 __attribute__((ext_vector_type(4)));

#define LOG2E 1.4426950408889634f
#define QSCALE (0.17677669529663687f * 1.4426950408889634f)

static __device__ __forceinline__ half4 cvt4h(float4 v) {
    half2v a = __builtin_bit_cast(half2v, __builtin_amdgcn_cvt_pkrtz(v.x, v.y));
    half2v b = __builtin_bit_cast(half2v, __builtin_amdgcn_cvt_pkrtz(v.z, v.w));
    return half4{ a[0], a[1], b[0], b[1] };
}

// ---------------- fused convert + prep (R15-verified) ----------------
#define NB_X 16384
#define NB_Y 16384
#define NB_W 512
#define NB_M 4096
#define NB_R 4096

__global__ __launch_bounds__(256) void convert_kernel(
    const float* __restrict__ x, const float* __restrict__ y,
    const float* __restrict__ q_w, const float* __restrict__ kv_w,
    const float* __restrict__ proj_w, const float* __restrict__ mask,
    const float* __restrict__ table, const int* __restrict__ rpi,
    _Float16* __restrict__ Xh, _Float16* __restrict__ Yh,
    _Float16* __restrict__ Wh, _Float16* __restrict__ maskh,
    _Float16* __restrict__ rpbh)
{
    const int blk = blockIdx.x, t = threadIdx.x;
    if (blk < NB_X + NB_Y) {
        const float* src; _Float16* dst; int v;
        if (blk < NB_X) { v = blk * 256 + t; src = x; dst = Xh; }
        else { v = (blk - NB_X) * 256 + t; src = y; dst = Yh; }
        int r = v >> 6, ks = (v & 63) * 8;
        const float* s = src + ((size_t)(r >> 8) * 512 + (size_t)((r & 255) * 2)) * 512 + ks;
        half4 h0 = cvt4h(*(const float4*)s);
        half4 h1 = cvt4h(*(const float4*)(s + 4));
        half8 hv = { h0[0], h0[1], h0[2], h0[3], h1[0], h1[1], h1[2], h1[3] };
        *(half8*)(dst + (size_t)v * 8) = hv;
    } else if (blk < NB_X + NB_Y + NB_W) {
        int v = (blk - NB_X - NB_Y) * 256 + t;
        int row = v >> 6, ks = (v & 63) * 8;
        const float* s; float sc = 1.0f;
        if (row < 512)       { s = q_w + (size_t)row * 512;            sc = QSCALE; }
        else if (row < 1536) { s = kv_w + (size_t)(row - 512) * 512; }
        else                 { s = proj_w + (size_t)(row - 1536) * 512; }
        float4 a = *(const float4*)(s + ks);
        float4 b = *(const float4*)(s + ks + 4);
        a.x *= sc; a.y *= sc; a.z *= sc; a.w *= sc;
        b.x *= sc; b.y *= sc; b.z *= sc; b.w *= sc;
        half4 h0 = cvt4h(a), h1 = cvt4h(b);
        half8 hv = { h0[0], h0[1], h0[2], h0[3], h1[0], h1[1], h1[2], h1[3] };
        *(half8*)(Wh + (size_t)v * 8) = hv;
    } else if (blk < NB_X + NB_Y + NB_W + NB_M) {
        int i = (blk - NB_X - NB_Y - NB_W) * 256 + t;
        float4 v = ((const float4*)mask)[i];
        half4 hv = { (_Float16)(v.x * LOG2E), (_Float16)(v.y * LOG2E),
                     (_Float16)(v.z * LOG2E), (_Float16)(v.w * LOG2E) };
        *(half4*)(maskh + (size_t)i * 4) = hv;
    } else {
        int i = (blk - NB_X - NB_Y - NB_W - NB_M) * 256 + t;
        int p = i & 65535, hh = i >> 16;
        rpbh[i] = (_Float16)(table[rpi[p] * 16 + hh] * LOG2E);
    }
}

// ---------------- pipelined f16 GEMM (R15-verified) --------------------------
// C[r][c] = A[r][:] . W[c][:] + bias, K=512, tile 128x128, BK=64.
// K-loop: barrier -> ds_write(kk) -> barrier -> issue loads kk+1 -> MFMA(kk).
// Epilogue (modes 0/1): acc -> LDS (swizzled) -> 1KB-contiguous stores.
// mode 0: Q; mode 1: K/V; mode 2: fp32 out + bias (direct 64B stores).
__global__ __launch_bounds__(256) void gemm_f16(
    const _Float16* __restrict__ Ah, const _Float16* __restrict__ Wh,
    const float* __restrict__ bias, float bscale,
    _Float16* __restrict__ qout, _Float16* __restrict__ kout,
    _Float16* __restrict__ vout, float* __restrict__ fout,
    int mode, int nct_sh)
{
    __shared__ __align__(16) _Float16 S[128 * 128];      // 32 KB
    _Float16* As = S;                                    // [128][64]
    _Float16* Ws = S + 128 * 64;                         // [128][64]
    const int nwg = gridDim.x;
    const int chunk = nwg >> 3;
    const int f = blockIdx.x;
    const int swz = (f & 7) * chunk + (f >> 3);
    const int ct = swz & ((1 << nct_sh) - 1);
    const int rt = swz >> nct_sh;

    const int t = threadIdx.x;
    const int lane = t & 63, wave = t >> 6;
    const int ql = lane & 15, g = lane >> 4;
    const int wr = (wave >> 1) * 64, wc = (wave & 1) * 64;

    const int sr = t >> 3;                 // 0..31
    const int st = t & 7;                  // source 16B slot (pre-swizzle)
    const _Float16* aR = Ah + ((size_t)(rt * 128 + sr)) * 512 + st * 8;
    const _Float16* wR = Wh + ((size_t)(ct * 128 + sr)) * 512 + st * 8;
    char* asw = (char*)As + sr * 128 + ((st ^ (sr & 7)) << 4);
    char* wsw = (char*)Ws + sr * 128 + ((st ^ (sr & 7)) << 4);

    // prologue: load K-step 0
    half8 a0 = *(const half8*)(aR);
    half8 a1 = *(const half8*)(aR + 32 * 512);
    half8 a2 = *(const half8*)(aR + 64 * 512);
    half8 a3 = *(const half8*)(aR + 96 * 512);
    half8 w0 = *(const half8*)(wR);
    half8 w1 = *(const half8*)(wR + 32 * 512);
    half8 w2 = *(const half8*)(wR + 64 * 512);
    half8 w3 = *(const half8*)(wR + 96 * 512);

    f32x4 acc[4][4] = {};
    for (int kk = 0; kk < 8; ++kk) {
        if (kk) __syncthreads();           // prior tile's LDS reads finished
        *(half8*)(asw)           = a0;
        *(half8*)(asw + 32*128)  = a1;
        *(half8*)(asw + 64*128)  = a2;
        *(half8*)(asw + 96*128)  = a3;
        *(half8*)(wsw)           = w0;
        *(half8*)(wsw + 32*128)  = w1;
        *(half8*)(wsw + 64*128)  = w2;
        *(half8*)(wsw + 96*128)  = w3;
        __syncthreads();
        if (kk < 7) {                      // issue next-tile loads EARLY
            const int k0n = (kk + 1) * 64;
            a0 = *(const half8*)(aR + k0n);
            a1 = *(const half8*)(aR + 32 * 512 + k0n);
            a2 = *(const half8*)(aR + 64 * 512 + k0n);
            a3 = *(const half8*)(aR + 96 * 512 + k0n);
            w0 = *(const half8*)(wR + k0n);
            w1 = *(const half8*)(wR + 32 * 512 + k0n);
            w2 = *(const half8*)(wR + 64 * 512 + k0n);
            w3 = *(const half8*)(wR + 96 * 512 + k0n);
        }
#pragma unroll
        for (int kh = 0; kh < 2; ++kh) {
            half8 af[4], bf[4];
#pragma unroll
            for (int i = 0; i < 4; ++i) {
                int row = wr + i * 16 + ql;
                af[i] = *(const half8*)((const char*)As + row * 128 +
                        (((kh * 4 + g) ^ (ql & 7)) << 4));
            }
#pragma unroll
            for (int j = 0; j < 4; ++j) {
                int row = wc + j * 16 + ql;
                bf[j] = *(const half8*)((const char*)Ws + row * 128 +
                        (((kh * 4 + g) ^ (ql & 7)) << 4));
            }
#pragma unroll
            for (int i = 0; i < 4; ++i)
#pragma unroll
                for (int j = 0; j < 4; ++j)
                    acc[i][j] = __builtin_amdgcn_mfma_f32_16x16x32_f16(af[i], bf[j], acc[i][j], 0, 0, 0);
        }
    }

    if (mode == 2) {
#pragma unroll
        for (int j = 0; j < 4; ++j) {
            int c = ct * 128 + wc + j * 16 + ql;
            float bv = bias[c];
#pragma unroll
            for (int i = 0; i < 4; ++i)
#pragma unroll
                for (int rr = 0; rr < 4; ++rr) {
                    int r = rt * 128 + wr + i * 16 + g * 4 + rr;
                    fout[(size_t)r * 512 + c] = acc[i][j][rr] + bv;
                }
        }
        return;
    }

    // ---- coalesced f16 epilogue: acc -> LDS (swizzled) -> 1KB stores ----
    __syncthreads();                       // K-loop LDS reads complete
#pragma unroll
    for (int j = 0; j < 4; ++j) {
        int col = wc + j * 16 + ql;
        float bv = bias[ct * 128 + col] * bscale;
#pragma unroll
        for (int i = 0; i < 4; ++i) {
#pragma unroll
            for (int rr = 0; rr < 4; ++rr) {
                int row = wr + i * 16 + g * 4 + rr;
                int scol = col ^ (((row >> 2) & 3) << 4);
                S[row * 128 + scol] = (_Float16)(acc[i][j][rr] + bv);
            }
        }
    }
    __syncthreads();
    {
        // wave owns col-block wave*32 (one head slice); 8 stores x 1KB
        const int c0 = ct * 128 + wave * 32;
        const int b = (rt * 128) >> 8, n0 = (rt * 128) & 255;
        _Float16* dst;
        int cc = c0;
        if (mode == 0) { dst = qout; }
        else if (c0 < 512) { dst = kout; }
        else { dst = vout; cc = c0 - 512; }
        const int hw = cc >> 5;
        _Float16* gb = dst + ((size_t)(b * 16 + hw) * 256 + n0) * 32;
        const int dq = (lane & 3) * 8;     // 16B chunk within the 32-d head
#pragma unroll
        for (int m = 0; m < 8; ++m) {
            int n = m * 16 + (lane >> 2);
            int colb = wave * 32 + dq;
            int scol = colb ^ (((n >> 2) & 3) << 4);
            half8 v = *(const half8*)(S + n * 128 + scol);
            *(half8*)(gb + (size_t)n * 32 + dq) = v;
        }
    }
}

// ---------------- fused window attention, one block per (window, head) -------
__global__ __launch_bounds__(256, 2) void attn_kernel(
    const _Float16* __restrict__ Q, const _Float16* __restrict__ K,
    const _Float16* __restrict__ V, const _Float16* __restrict__ rpbh,
    const _Float16* __restrict__ maskh, _Float16* __restrict__ pre)
{
    __shared__ __align__(16) _Float16 bias_s[2][16 * 256];   // 2 x 8 KB
    const int blk = blockIdx.x;
    const int w = blk >> 4, h = blk & 15;
    const int t = threadIdx.x;
    const int lane = t & 63, wave = t >> 6;
    const int ql = lane & 15, g = lane >> 4;
    const int b = w + 64 * wave;
    const size_t blk_b = (size_t)(b * 16 + h) * 8192;
    const _Float16* Qp = Q + blk_b + g * 8;
    const _Float16* Kp = K + blk_b + ql * 32 + g * 8;
    const _Float16* rp = rpbh + (size_t)h * 65536;
    const _Float16* mp = maskh + (size_t)w * 65536;

    half8 karr[16];
#pragma unroll
    for (int tt = 0; tt < 16; ++tt)
        karr[tt] = *(const half8*)(Kp + tt * 512);

    half4 vf0[16], vf1[16];
    {
        const _Float16* vb = V + blk_b + g * 128 + ql;
#pragma unroll
        for (int tt = 0; tt < 16; ++tt) {
#pragma unroll
            for (int j = 0; j < 4; ++j) {
                vf0[tt][j] = vb[tt * 512 + j * 32];
                vf1[tt][j] = vb[tt * 512 + j * 32 + 16];
            }
        }
    }

    const int sq = t >> 4;
    const int scb = (t & 15) * 32;
    const int sw = sq << 3;
    const int sgoff = (t & 15) * 16;

    {
        const _Float16* rrow = rp + (size_t)sq * 256 + sgoff;
        const _Float16* mrow = mp + (size_t)sq * 256 + sgoff;
        half8 s0 = *(const half8*)rrow + *(const half8*)mrow;
        half8 s1 = *(const half8*)(rrow + 8) + *(const half8*)(mrow + 8);
        char* sb = (char*)bias_s[0] + sq * 512;
        *(half4*)(sb + ((scb) ^ sw))      = __builtin_shufflevector(s0, s0, 0, 1, 2, 3);
        *(half4*)(sb + ((scb + 8) ^ sw))  = __builtin_shufflevector(s0, s0, 4, 5, 6, 7);
        *(half4*)(sb + ((scb + 16) ^ sw)) = __builtin_shufflevector(s1, s1, 0, 1, 2, 3);
        *(half4*)(sb + ((scb + 24) ^ sw)) = __builtin_shufflevector(s1, s1, 4, 5, 6, 7);
    }
    __syncthreads();

#pragma unroll 1
    for (int qg = 0; qg < 16; ++qg) {
        const int q0 = qg * 16;
        half8 nr0, nm0, nr1, nm1;
        if (qg < 15) {
            const _Float16* rrow = rp + (size_t)(q0 + 16 + sq) * 256 + sgoff;
            const _Float16* mrow = mp + (size_t)(q0 + 16 + sq) * 256 + sgoff;
            nr0 = *(const half8*)rrow;
            nm0 = *(const half8*)mrow;
            nr1 = *(const half8*)(rrow + 8);
            nm1 = *(const half8*)(mrow + 8);
        }

        const int q = q0 + ql;
        half8 qf = *(const half8*)(Qp + (size_t)q * 32);
        const char* bb = (const char*)bias_s[qg & 1] + ql * 512;
        f32x4 lsum = { 0.f, 0.f, 0.f, 0.f };
        f32x4 o0 = { 0.f, 0.f, 0.f, 0.f }, o1 = { 0.f, 0.f, 0.f, 0.f };
#pragma unroll
        for (int tt = 0; tt < 16; ++tt) {
            half4 bs = *(const half4*)(bb + ((tt * 32 + g * 8) ^ (ql << 3)));
            f32x4 bf = { (float)bs[0], (float)bs[1], (float)bs[2], (float)bs[3] };
            f32x4 s = __builtin_amdgcn_mfma_f32_16x16x32_f16(karr[tt], qf, bf, 0, 0, 0);
            float e0 = __builtin_amdgcn_exp2f(s[0]);
            float e1 = __builtin_amdgcn_exp2f(s[1]);
            float e2 = __builtin_amdgcn_exp2f(s[2]);
            float e3 = __builtin_amdgcn_exp2f(s[3]);
            lsum[0] += e0; lsum[1] += e1; lsum[2] += e2; lsum[3] += e3;
            half2v p01 = __builtin_bit_cast(half2v, __builtin_amdgcn_cvt_pkrtz(e0, e1));
            half2v p23 = __builtin_bit_cast(half2v, __builtin_amdgcn_cvt_pkrtz(e2, e3));
            half4 pf = { p01[0], p01[1], p23[0], p23[1] };
            o0 = __builtin_amdgcn_mfma_f32_16x16x16f16(pf, vf0[tt], o0, 0, 0, 0);
            o1 = __builtin_amdgcn_mfma_f32_16x16x16f16(pf, vf1[tt], o1, 0, 0, 0);
        }
        float l = (lsum[0] + lsum[1]) + (lsum[2] + lsum[3]);
        l += __shfl_xor(l, 16);
        l += __shfl_xor(l, 32);
#pragma unroll
        for (int rr = 0; rr < 4; ++rr) {
            float inv = __builtin_amdgcn_rcpf(__shfl(l, g * 4 + rr));
            int row = q0 + g * 4 + rr;
            size_t ob = ((size_t)b * 256 + row) * 512 + h * 32;
            pre[ob + ql] = (_Float16)(o0[rr] * inv);
            pre[ob + 16 + ql] = (_Float16)(o1[rr] * inv);
        }
        if (qg < 15) {
            half8 s0 = nr0 + nm0, s1 = nr1 + nm1;
            char* sb = (char*)bias_s[(qg + 1) & 1] + sq * 512;
            *(half4*)(sb + ((scb) ^ sw))      = __builtin_shufflevector(s0, s0, 0, 1, 2, 3);
            *(half4*)(sb + ((scb + 8) ^ sw))  = __builtin_shufflevector(s0, s0, 4, 5, 6, 7);
            *(half4*)(sb + ((scb + 16) ^ sw)) = __builtin_shufflevector(s1, s1, 0, 1, 2, 3);
            *(half4*)(sb + ((scb + 24) ^ sw)) = __builtin_shufflevector(s1, s1, 4, 5, 6, 7);
        }
        __syncthreads();
    }
}

extern "C" void kernel_launch(void* const* d_in, const int* in_sizes, int n_in,
                              void* d_out, int out_size, void* d_ws, size_t ws_size,
                              hipStream_t stream)
{
    const float* x      = (const float*)d_in[0];
    const float* y      = (const float*)d_in[1];
    const float* mask   = (const float*)d_in[2];
    const float* q_w    = (const float*)d_in[3];
    const float* q_b    = (const float*)d_in[4];
    const float* kv_w   = (const float*)d_in[5];
    const float* kv_b   = (const float*)d_in[6];
    const float* proj_w = (const float*)d_in[7];
    const float* proj_b = (const float*)d_in[8];
    const float* btab   = (const float*)d_in[9];
    const int*   rpi    = (const int*)d_in[10];
    float* out = (float*)d_out;

    char* ws = (char*)d_ws;
    // aliased regions (sequential kernel ordering makes reuse safe):
    _Float16* XK  = (_Float16*)(ws);                       // Xh, then K
    _Float16* YP  = (_Float16*)(ws + ((size_t)64 << 20));  // Yh, then Pre
    _Float16* Qw  = (_Float16*)(ws + ((size_t)128 << 20));
    _Float16* Vw  = (_Float16*)(ws + ((size_t)192 << 20));
    _Float16* Wh  = (_Float16*)(ws + ((size_t)256 << 20));              // 2 MiB
    _Float16* Rpb = (_Float16*)(ws + ((size_t)258 << 20));              // 2 MiB
    _Float16* Mh  = (_Float16*)(ws + ((size_t)260 << 20));              // 8 MiB

    convert_kernel<<<NB_X + NB_Y + NB_W + NB_M + NB_R, 256, 0, stream>>>(
        x, y, q_w, kv_w, proj_w, mask, btab, rpi, XK, YP, Wh, Mh, Rpb);
    // Q projection: Xh @ Wq^T (Wq pre-scaled by QSCALE)
    gemm_f16<<<2048, 256, 0, stream>>>(XK, Wh, q_b, QSCALE,
                                       Qw, nullptr, nullptr, nullptr, 0, 2);
    // KV projection: Yh @ Wkv^T  (K overwrites Xh — dead after Q-proj)
    gemm_f16<<<4096, 256, 0, stream>>>(YP, Wh + 512 * 512, kv_b, 1.0f,
                                       nullptr, XK, Vw, nullptr, 1, 3);
    // attention (Pre overwrites Yh — dead after KV-proj)
    attn_kernel<<<1024, 256, 0, stream>>>(Qw, XK, Vw, Rpb, Mh, YP);
    // output projection
    gemm_f16<<<2048, 256, 0, stream>>>(YP, Wh + 1536 * 512, proj_b, 1.0f,
                                       nullptr, nullptr, nullptr, out, 2, 2);
}

// Round 21
// 415.186 us; speedup vs baseline: 1.0601x; 1.0076x over previous
//
#include <hip/hip_runtime.h>

typedef _Float16 half8 __attribute__((ext_vector_type(8)));
typedef _Float16 half4 __attribute__((ext_vector_type(4)));
typedef _Float16 half2v __attribute__((ext_vector_type(2)));
typedef float f32x4 __attribute__((ext_vector_type(4)));

#define LOG2E 1.4426950408889634f
#define QSCALE (0.17677669529663687f * 1.4426950408889634f)

static __device__ __forceinline__ half4 cvt4h(float4 v) {
    half2v a = __builtin_bit_cast(half2v, __builtin_amdgcn_cvt_pkrtz(v.x, v.y));
    half2v b = __builtin_bit_cast(half2v, __builtin_amdgcn_cvt_pkrtz(v.z, v.w));
    return half4{ a[0], a[1], b[0], b[1] };
}

// ---------------- fused convert + prep (R15-verified) ----------------
#define NB_X 16384
#define NB_Y 16384
#define NB_W 512
#define NB_M 4096
#define NB_R 4096

__global__ __launch_bounds__(256) void convert_kernel(
    const float* __restrict__ x, const float* __restrict__ y,
    const float* __restrict__ q_w, const float* __restrict__ kv_w,
    const float* __restrict__ proj_w, const float* __restrict__ mask,
    const float* __restrict__ table, const int* __restrict__ rpi,
    _Float16* __restrict__ Xh, _Float16* __restrict__ Yh,
    _Float16* __restrict__ Wh, _Float16* __restrict__ maskh,
    _Float16* __restrict__ rpbh)
{
    const int blk = blockIdx.x, t = threadIdx.x;
    if (blk < NB_X + NB_Y) {
        const float* src; _Float16* dst; int v;
        if (blk < NB_X) { v = blk * 256 + t; src = x; dst = Xh; }
        else { v = (blk - NB_X) * 256 + t; src = y; dst = Yh; }
        int r = v >> 6, ks = (v & 63) * 8;
        const float* s = src + ((size_t)(r >> 8) * 512 + (size_t)((r & 255) * 2)) * 512 + ks;
        half4 h0 = cvt4h(*(const float4*)s);
        half4 h1 = cvt4h(*(const float4*)(s + 4));
        half8 hv = { h0[0], h0[1], h0[2], h0[3], h1[0], h1[1], h1[2], h1[3] };
        *(half8*)(dst + (size_t)v * 8) = hv;
    } else if (blk < NB_X + NB_Y + NB_W) {
        int v = (blk - NB_X - NB_Y) * 256 + t;
        int row = v >> 6, ks = (v & 63) * 8;
        const float* s; float sc = 1.0f;
        if (row < 512)       { s = q_w + (size_t)row * 512;            sc = QSCALE; }
        else if (row < 1536) { s = kv_w + (size_t)(row - 512) * 512; }
        else                 { s = proj_w + (size_t)(row - 1536) * 512; }
        float4 a = *(const float4*)(s + ks);
        float4 b = *(const float4*)(s + ks + 4);
        a.x *= sc; a.y *= sc; a.z *= sc; a.w *= sc;
        b.x *= sc; b.y *= sc; b.z *= sc; b.w *= sc;
        half4 h0 = cvt4h(a), h1 = cvt4h(b);
        half8 hv = { h0[0], h0[1], h0[2], h0[3], h1[0], h1[1], h1[2], h1[3] };
        *(half8*)(Wh + (size_t)v * 8) = hv;
    } else if (blk < NB_X + NB_Y + NB_W + NB_M) {
        int i = (blk - NB_X - NB_Y - NB_W) * 256 + t;
        float4 v = ((const float4*)mask)[i];
        half4 hv = { (_Float16)(v.x * LOG2E), (_Float16)(v.y * LOG2E),
                     (_Float16)(v.z * LOG2E), (_Float16)(v.w * LOG2E) };
        *(half4*)(maskh + (size_t)i * 4) = hv;
    } else {
        int i = (blk - NB_X - NB_Y - NB_W - NB_M) * 256 + t;
        int p = i & 65535, hh = i >> 16;
        rpbh[i] = (_Float16)(table[rpi[p] * 16 + hh] * LOG2E);
    }
}

// ---------------- pipelined f16 GEMM (R15-verified) --------------------------
// C[r][c] = A[r][:] . W[c][:] + bias, K=512, tile 128x128, BK=64.
// K-loop: barrier -> ds_write(kk) -> barrier -> issue loads kk+1 -> MFMA(kk).
// Epilogue (modes 0/1): acc -> LDS (swizzled) -> 1KB-contiguous stores.
// mode 0: Q; mode 1: K/V; mode 2: fp32 out + bias (direct 64B stores).
__global__ __launch_bounds__(256) void gemm_f16(
    const _Float16* __restrict__ Ah, const _Float16* __restrict__ Wh,
    const float* __restrict__ bias, float bscale,
    _Float16* __restrict__ qout, _Float16* __restrict__ kout,
    _Float16* __restrict__ vout, float* __restrict__ fout,
    int mode, int nct_sh)
{
    __shared__ __align__(16) _Float16 S[128 * 128];      // 32 KB
    _Float16* As = S;                                    // [128][64]
    _Float16* Ws = S + 128 * 64;                         // [128][64]
    const int nwg = gridDim.x;
    const int chunk = nwg >> 3;
    const int f = blockIdx.x;
    const int swz = (f & 7) * chunk + (f >> 3);
    const int ct = swz & ((1 << nct_sh) - 1);
    const int rt = swz >> nct_sh;

    const int t = threadIdx.x;
    const int lane = t & 63, wave = t >> 6;
    const int ql = lane & 15, g = lane >> 4;
    const int wr = (wave >> 1) * 64, wc = (wave & 1) * 64;

    const int sr = t >> 3;                 // 0..31
    const int st = t & 7;                  // source 16B slot (pre-swizzle)
    const _Float16* aR = Ah + ((size_t)(rt * 128 + sr)) * 512 + st * 8;
    const _Float16* wR = Wh + ((size_t)(ct * 128 + sr)) * 512 + st * 8;
    char* asw = (char*)As + sr * 128 + ((st ^ (sr & 7)) << 4);
    char* wsw = (char*)Ws + sr * 128 + ((st ^ (sr & 7)) << 4);

    // prologue: load K-step 0
    half8 a0 = *(const half8*)(aR);
    half8 a1 = *(const half8*)(aR + 32 * 512);
    half8 a2 = *(const half8*)(aR + 64 * 512);
    half8 a3 = *(const half8*)(aR + 96 * 512);
    half8 w0 = *(const half8*)(wR);
    half8 w1 = *(const half8*)(wR + 32 * 512);
    half8 w2 = *(const half8*)(wR + 64 * 512);
    half8 w3 = *(const half8*)(wR + 96 * 512);

    f32x4 acc[4][4] = {};
    for (int kk = 0; kk < 8; ++kk) {
        if (kk) __syncthreads();           // prior tile's LDS reads finished
        *(half8*)(asw)           = a0;
        *(half8*)(asw + 32*128)  = a1;
        *(half8*)(asw + 64*128)  = a2;
        *(half8*)(asw + 96*128)  = a3;
        *(half8*)(wsw)           = w0;
        *(half8*)(wsw + 32*128)  = w1;
        *(half8*)(wsw + 64*128)  = w2;
        *(half8*)(wsw + 96*128)  = w3;
        __syncthreads();
        if (kk < 7) {                      // issue next-tile loads EARLY
            const int k0n = (kk + 1) * 64;
            a0 = *(const half8*)(aR + k0n);
            a1 = *(const half8*)(aR + 32 * 512 + k0n);
            a2 = *(const half8*)(aR + 64 * 512 + k0n);
            a3 = *(const half8*)(aR + 96 * 512 + k0n);
            w0 = *(const half8*)(wR + k0n);
            w1 = *(const half8*)(wR + 32 * 512 + k0n);
            w2 = *(const half8*)(wR + 64 * 512 + k0n);
            w3 = *(const half8*)(wR + 96 * 512 + k0n);
        }
#pragma unroll
        for (int kh = 0; kh < 2; ++kh) {
            half8 af[4], bf[4];
#pragma unroll
            for (int i = 0; i < 4; ++i) {
                int row = wr + i * 16 + ql;
                af[i] = *(const half8*)((const char*)As + row * 128 +
                        (((kh * 4 + g) ^ (ql & 7)) << 4));
            }
#pragma unroll
            for (int j = 0; j < 4; ++j) {
                int row = wc + j * 16 + ql;
                bf[j] = *(const half8*)((const char*)Ws + row * 128 +
                        (((kh * 4 + g) ^ (ql & 7)) << 4));
            }
#pragma unroll
            for (int i = 0; i < 4; ++i)
#pragma unroll
                for (int j = 0; j < 4; ++j)
                    acc[i][j] = __builtin_amdgcn_mfma_f32_16x16x32_f16(af[i], bf[j], acc[i][j], 0, 0, 0);
        }
    }

    if (mode == 2) {
#pragma unroll
        for (int j = 0; j < 4; ++j) {
            int c = ct * 128 + wc + j * 16 + ql;
            float bv = bias[c];
#pragma unroll
            for (int i = 0; i < 4; ++i)
#pragma unroll
                for (int rr = 0; rr < 4; ++rr) {
                    int r = rt * 128 + wr + i * 16 + g * 4 + rr;
                    fout[(size_t)r * 512 + c] = acc[i][j][rr] + bv;
                }
        }
        return;
    }

    // ---- coalesced f16 epilogue: acc -> LDS (swizzled) -> 1KB stores ----
    __syncthreads();                       // K-loop LDS reads complete
#pragma unroll
    for (int j = 0; j < 4; ++j) {
        int col = wc + j * 16 + ql;
        float bv = bias[ct * 128 + col] * bscale;
#pragma unroll
        for (int i = 0; i < 4; ++i) {
#pragma unroll
            for (int rr = 0; rr < 4; ++rr) {
                int row = wr + i * 16 + g * 4 + rr;
                int scol = col ^ (((row >> 2) & 3) << 4);
                S[row * 128 + scol] = (_Float16)(acc[i][j][rr] + bv);
            }
        }
    }
    __syncthreads();
    {
        // wave owns col-block wave*32 (one head slice); 8 stores x 1KB
        const int c0 = ct * 128 + wave * 32;
        const int b = (rt * 128) >> 8, n0 = (rt * 128) & 255;
        _Float16* dst;
        int cc = c0;
        if (mode == 0) { dst = qout; }
        else if (c0 < 512) { dst = kout; }
        else { dst = vout; cc = c0 - 512; }
        const int hw = cc >> 5;
        _Float16* gb = dst + ((size_t)(b * 16 + hw) * 256 + n0) * 32;
        const int dq = (lane & 3) * 8;     // 16B chunk within the 32-d head
#pragma unroll
        for (int m = 0; m < 8; ++m) {
            int n = m * 16 + (lane >> 2);
            int colb = wave * 32 + dq;
            int scol = colb ^ (((n >> 2) & 3) << 4);
            half8 v = *(const half8*)(S + n * 128 + scol);
            *(half8*)(gb + (size_t)n * 32 + dq) = v;
        }
    }
}

// ---------------- fused window attention, one block per (window, head) -------
__global__ __launch_bounds__(256, 2) void attn_kernel(
    const _Float16* __restrict__ Q, const _Float16* __restrict__ K,
    const _Float16* __restrict__ V, const _Float16* __restrict__ rpbh,
    const _Float16* __restrict__ maskh, _Float16* __restrict__ pre)
{
    __shared__ __align__(16) _Float16 bias_s[2][16 * 256];   // 2 x 8 KB
    const int blk = blockIdx.x;
    const int w = blk >> 4, h = blk & 15;
    const int t = threadIdx.x;
    const int lane = t & 63, wave = t >> 6;
    const int ql = lane & 15, g = lane >> 4;
    const int b = w + 64 * wave;
    const size_t blk_b = (size_t)(b * 16 + h) * 8192;
    const _Float16* Qp = Q + blk_b + g * 8;
    const _Float16* Kp = K + blk_b + ql * 32 + g * 8;
    const _Float16* rp = rpbh + (size_t)h * 65536;
    const _Float16* mp = maskh + (size_t)w * 65536;

    half8 karr[16];
#pragma unroll
    for (int tt = 0; tt < 16; ++tt)
        karr[tt] = *(const half8*)(Kp + tt * 512);

    half4 vf0[16], vf1[16];
    {
        const _Float16* vb = V + blk_b + g * 128 + ql;
#pragma unroll
        for (int tt = 0; tt < 16; ++tt) {
#pragma unroll
            for (int j = 0; j < 4; ++j) {
                vf0[tt][j] = vb[tt * 512 + j * 32];
                vf1[tt][j] = vb[tt * 512 + j * 32 + 16];
            }
        }
    }

    const int sq = t >> 4;
    const int scb = (t & 15) * 32;
    const int sw = sq << 3;
    const int sgoff = (t & 15) * 16;

    {
        const _Float16* rrow = rp + (size_t)sq * 256 + sgoff;
        const _Float16* mrow = mp + (size_t)sq * 256 + sgoff;
        half8 s0 = *(const half8*)rrow + *(const half8*)mrow;
        half8 s1 = *(const half8*)(rrow + 8) + *(const half8*)(mrow + 8);
        char* sb = (char*)bias_s[0] + sq * 512;
        *(half4*)(sb + ((scb) ^ sw))      = __builtin_shufflevector(s0, s0, 0, 1, 2, 3);
        *(half4*)(sb + ((scb + 8) ^ sw))  = __builtin_shufflevector(s0, s0, 4, 5, 6, 7);
        *(half4*)(sb + ((scb + 16) ^ sw)) = __builtin_shufflevector(s1, s1, 0, 1, 2, 3);
        *(half4*)(sb + ((scb + 24) ^ sw)) = __builtin_shufflevector(s1, s1, 4, 5, 6, 7);
    }
    __syncthreads();

#pragma unroll 1
    for (int qg = 0; qg < 16; ++qg) {
        const int q0 = qg * 16;
        half8 nr0, nm0, nr1, nm1;
        if (qg < 15) {
            const _Float16* rrow = rp + (size_t)(q0 + 16 + sq) * 256 + sgoff;
            const _Float16* mrow = mp + (size_t)(q0 + 16 + sq) * 256 + sgoff;
            nr0 = *(const half8*)rrow;
            nm0 = *(const half8*)mrow;
            nr1 = *(const half8*)(rrow + 8);
            nm1 = *(const half8*)(mrow + 8);
        }

        const int q = q0 + ql;
        half8 qf = *(const half8*)(Qp + (size_t)q * 32);
        const char* bb = (const char*)bias_s[qg & 1] + ql * 512;
        f32x4 lsum = { 0.f, 0.f, 0.f, 0.f };
        f32x4 o0 = { 0.f, 0.f, 0.f, 0.f }, o1 = { 0.f, 0.f, 0.f, 0.f };
#pragma unroll
        for (int tt = 0; tt < 16; ++tt) {
            half4 bs = *(const half4*)(bb + ((tt * 32 + g * 8) ^ (ql << 3)));
            f32x4 bf = { (float)bs[0], (float)bs[1], (float)bs[2], (float)bs[3] };
            f32x4 s = __builtin_amdgcn_mfma_f32_16x16x32_f16(karr[tt], qf, bf, 0, 0, 0);
            float e0 = __builtin_amdgcn_exp2f(s[0]);
            float e1 = __builtin_amdgcn_exp2f(s[1]);
            float e2 = __builtin_amdgcn_exp2f(s[2]);
            float e3 = __builtin_amdgcn_exp2f(s[3]);
            lsum[0] += e0; lsum[1] += e1; lsum[2] += e2; lsum[3] += e3;
            half2v p01 = __builtin_bit_cast(half2v, __builtin_amdgcn_cvt_pkrtz(e0, e1));
            half2v p23 = __builtin_bit_cast(half2v, __builtin_amdgcn_cvt_pkrtz(e2, e3));
            half4 pf = { p01[0], p01[1], p23[0], p23[1] };
            o0 = __builtin_amdgcn_mfma_f32_16x16x16f16(pf, vf0[tt], o0, 0, 0, 0);
            o1 = __builtin_amdgcn_mfma_f32_16x16x16f16(pf, vf1[tt], o1, 0, 0, 0);
        }
        float l = (lsum[0] + lsum[1]) + (lsum[2] + lsum[3]);
        l += __shfl_xor(l, 16);
        l += __shfl_xor(l, 32);
#pragma unroll
        for (int rr = 0; rr < 4; ++rr) {
            float inv = __builtin_amdgcn_rcpf(__shfl(l, g * 4 + rr));
            int row = q0 + g * 4 + rr;
            size_t ob = ((size_t)b * 256 + row) * 512 + h * 32;
            pre[ob + ql] = (_Float16)(o0[rr] * inv);
            pre[ob + 16 + ql] = (_Float16)(o1[rr] * inv);
        }
        if (qg < 15) {
            half8 s0 = nr0 + nm0, s1 = nr1 + nm1;
            char* sb = (char*)bias_s[(qg + 1) & 1] + sq * 512;
            *(half4*)(sb + ((scb) ^ sw))      = __builtin_shufflevector(s0, s0, 0, 1, 2, 3);
            *(half4*)(sb + ((scb + 8) ^ sw))  = __builtin_shufflevector(s0, s0, 4, 5, 6, 7);
            *(half4*)(sb + ((scb + 16) ^ sw)) = __builtin_shufflevector(s1, s1, 0, 1, 2, 3);
            *(half4*)(sb + ((scb + 24) ^ sw)) = __builtin_shufflevector(s1, s1, 4, 5, 6, 7);
        }
        __syncthreads();
    }
}

extern "C" void kernel_launch(void* const* d_in, const int* in_sizes, int n_in,
                              void* d_out, int out_size, void* d_ws, size_t ws_size,
                              hipStream_t stream)
{
    const float* x      = (const float*)d_in[0];
    const float* y      = (const float*)d_in[1];
    const float* mask   = (const float*)d_in[2];
    const float* q_w    = (const float*)d_in[3];
    const float* q_b    = (const float*)d_in[4];
    const float* kv_w   = (const float*)d_in[5];
    const float* kv_b   = (const float*)d_in[6];
    const float* proj_w = (const float*)d_in[7];
    const float* proj_b = (const float*)d_in[8];
    const float* btab   = (const float*)d_in[9];
    const int*   rpi    = (const int*)d_in[10];
    float* out = (float*)d_out;

    char* ws = (char*)d_ws;
    // aliased regions (sequential kernel ordering makes reuse safe):
    _Float16* XK  = (_Float16*)(ws);                       // Xh, then K
    _Float16* YP  = (_Float16*)(ws + ((size_t)64 << 20));  // Yh, then Pre
    _Float16* Qw  = (_Float16*)(ws + ((size_t)128 << 20));
    _Float16* Vw  = (_Float16*)(ws + ((size_t)192 << 20));
    _Float16* Wh  = (_Float16*)(ws + ((size_t)256 << 20));              // 2 MiB
    _Float16* Rpb = (_Float16*)(ws + ((size_t)258 << 20));              // 2 MiB
    _Float16* Mh  = (_Float16*)(ws + ((size_t)260 << 20));              // 8 MiB

    convert_kernel<<<NB_X + NB_Y + NB_W + NB_M + NB_R, 256, 0, stream>>>(
        x, y, q_w, kv_w, proj_w, mask, btab, rpi, XK, YP, Wh, Mh, Rpb);
    // Q projection: Xh @ Wq^T (Wq pre-scaled by QSCALE)
    gemm_f16<<<2048, 256, 0, stream>>>(XK, Wh, q_b, QSCALE,
                                       Qw, nullptr, nullptr, nullptr, 0, 2);
    // KV projection: Yh @ Wkv^T  (K overwrites Xh — dead after Q-proj)
    gemm_f16<<<4096, 256, 0, stream>>>(YP, Wh + 512 * 512, kv_b, 1.0f,
                                       nullptr, XK, Vw, nullptr, 1, 3);
    // attention (Pre overwrites Yh — dead after KV-proj)
    attn_kernel<<<1024, 256, 0, stream>>>(Qw, XK, Vw, Rpb, Mh, YP);
    // output projection
    gemm_f16<<<2048, 256, 0, stream>>>(YP, Wh + 1536 * 512, proj_b, 1.0f,
                                       nullptr, nullptr, nullptr, out, 2, 2);
}